// Round 19
// baseline (310.467 us; speedup 1.0000x reference)
//
#include <hip/hip_runtime.h>
#include <hip/hip_bf16.h>
#include <stdint.h>

#define B_ 2
#define D_ 128
#define H_ 512
#define W_ 512
#define G_ 60
#define NQ_ 7200
#define BORDER_ 16
#define STEP_ 8

typedef __attribute__((ext_vector_type(8))) short short8;
typedef __attribute__((ext_vector_type(4))) float f32x4;
typedef __attribute__((ext_vector_type(4))) uint32_t u32x4;

__device__ __forceinline__ float bf_lo(uint32_t u){ return __builtin_bit_cast(float, u << 16); }
__device__ __forceinline__ float bf_hi(uint32_t u){ return __builtin_bit_cast(float, u & 0xffff0000u); }

__device__ __forceinline__ uint32_t pack2bf(float lo, float hi){
  uint16_t l = __builtin_bit_cast(uint16_t, __float2bfloat16(lo));
  uint16_t h = __builtin_bit_cast(uint16_t, __float2bfloat16(hi));
  return (uint32_t)l | ((uint32_t)h << 16);
}

// ---------------- gt region zero-fill (aligned full-line nt float4 stream) ----------------
__global__ __launch_bounds__(256) void gtzero_k(f32x4* __restrict__ gt, size_t n4){
  size_t i = (size_t)blockIdx.x * 256 + threadIdx.x;
  size_t stride = (size_t)gridDim.x * 256;
  f32x4 z = {0.f, 0.f, 0.f, 0.f};
  for (; i < n4; i += stride)
    __builtin_nontemporal_store(z, gt + i);
}

// ---------------- feat2 (B,D,H,W) f32 -> (B,H,W,D) bf16 ----------------
__global__ __launch_bounds__(256) void transpose_k(const float* __restrict__ src,
                                                   __hip_bfloat16* __restrict__ dst){
  __shared__ uint32_t lds2[64][65];
  int b = blockIdx.z, y = blockIdx.y, x0 = blockIdx.x * 64;
  int tid = threadIdx.x;
  size_t plane = (size_t)H_ * W_;

  int xq = tid & 15;        // x-quad (4 floats)
  int eg = tid >> 4;        // 0..15
  size_t base_in = (((size_t)b * D_) * H_ + y) * W_ + x0 + 4 * xq;
  #pragma unroll
  for (int it = 0; it < 4; ++it){
    int e = eg + 16 * it;   // d-pair 0..63
    f32x4 lo = __builtin_nontemporal_load(
        reinterpret_cast<const f32x4*>(src + base_in + (size_t)(2 * e) * plane));
    f32x4 hi = __builtin_nontemporal_load(
        reinterpret_cast<const f32x4*>(src + base_in + (size_t)(2 * e + 1) * plane));
    lds2[e][4 * xq + 0] = pack2bf(lo[0], hi[0]);
    lds2[e][4 * xq + 1] = pack2bf(lo[1], hi[1]);
    lds2[e][4 * xq + 2] = pack2bf(lo[2], hi[2]);
    lds2[e][4 * xq + 3] = pack2bf(lo[3], hi[3]);
  }
  __syncthreads();

  int eq = tid & 15;        // u32-quad within a pixel's 64-u32 row
  int xb = tid >> 4;        // 0..15
  size_t pixbase = (((size_t)b * H_ + y) * W_ + x0);
  #pragma unroll
  for (int it = 0; it < 4; ++it){
    int x = xb + 16 * it;
    u32x4 v;
    v[0] = lds2[4 * eq + 0][x];
    v[1] = lds2[4 * eq + 1][x];
    v[2] = lds2[4 * eq + 2][x];
    v[3] = lds2[4 * eq + 3][x];
    *reinterpret_cast<u32x4*>(dst + (pixbase + x) * D_ + 8 * eq) = v;
  }
}

// ---------------- per-query prep: f1, d3, xy tables, mask, qconf ----------------
template<bool USE_T>
__global__ __launch_bounds__(128) void prep_k(
    const float* __restrict__ feat1, const float* __restrict__ feat2,
    const __hip_bfloat16* __restrict__ f2t,
    const float* __restrict__ conf1, const float* __restrict__ aflow,
    __hip_bfloat16* __restrict__ f1o, __hip_bfloat16* __restrict__ d3o,
    float2* __restrict__ qxy, float2* __restrict__ dxy,
    float* __restrict__ omask, float* __restrict__ oqconf)
{
  int n = blockIdx.x;
  int b = n / (G_ * G_); int r = n % (G_ * G_);
  int iy = r / G_, ix = r % G_;
  int y1 = BORDER_ + iy * STEP_, x1 = BORDER_ + ix * STEP_;
  int tid = threadIdx.x;
  size_t pix = ((size_t)b * H_ + y1) * W_ + x1;
  if (tid < 64){
    int d = tid * 2;
    size_t o = (((size_t)b * D_ + d) * H_ + y1) * W_ + x1;
    float lo = feat1[o];
    float hi = feat1[o + (size_t)H_ * W_];
    *reinterpret_cast<uint32_t*>(f1o + (size_t)n * D_ + d) = pack2bf(lo, hi);
    if (tid == 0){
      float ax = aflow[(((size_t)b * 2 + 0) * H_ + y1) * W_ + x1];
      float ay = aflow[(((size_t)b * 2 + 1) * H_ + y1) * W_ + x1];
      int x2 = (int)(ax + 0.5f);   // trunc toward zero == astype(int32)
      int y2 = (int)(ay + 0.5f);
      omask[n] = (x2 >= 0 && y2 >= 0 && x2 < W_ && y2 < H_) ? 1.0f : 0.0f;
      oqconf[n] = conf1[pix];
      float bs = 512.0f * (float)b;
      qxy[n] = make_float2((float)x2 + bs, (float)y2 + bs);
      dxy[n] = make_float2((float)x1 + bs, (float)y1 + bs);
    }
  } else {
    int d = (tid - 64) * 2;
    uint32_t u;
    if (USE_T){
      u = *reinterpret_cast<const uint32_t*>(f2t + pix * D_ + d);
    } else {
      size_t o = (((size_t)b * D_ + d) * H_ + y1) * W_ + x1;
      u = pack2bf(feat2[o], feat2[o + (size_t)H_ * W_]);
    }
    *reinterpret_cast<uint32_t*>(d3o + (size_t)n * D_ + d) = u;
  }
}

// ---------------- pos/neg neighbor scores + gt cols 0..P+NN-1 ----------------
template<bool USE_T>
__global__ __launch_bounds__(256) void posneg_k(
    const __hip_bfloat16* __restrict__ f1o,
    const __hip_bfloat16* __restrict__ f2t,
    const float* __restrict__ feat2,
    const float* __restrict__ aflow,
    const int* __restrict__ pos, const int* __restrict__ neg,
    int P, int NN, float* __restrict__ out, int NCOL, size_t GTOFF)
{
  int n = blockIdx.x;
  int b = n / (G_ * G_); int r = n % (G_ * G_);
  int iy = r / G_, ix = r % G_;
  int y1 = BORDER_ + iy * STEP_, x1 = BORDER_ + ix * STEP_;
  int tid = threadIdx.x;
  int l16 = tid & 15, grp = tid >> 4;

  const uint4 av = *reinterpret_cast<const uint4*>(f1o + (size_t)n * D_ + l16 * 8);
  float a[8];
  a[0] = bf_lo(av.x); a[1] = bf_hi(av.x); a[2] = bf_lo(av.y); a[3] = bf_hi(av.y);
  a[4] = bf_lo(av.z); a[5] = bf_hi(av.z); a[6] = bf_lo(av.w); a[7] = bf_hi(av.w);

  float ax = aflow[(((size_t)b * 2 + 0) * H_ + y1) * W_ + x1];
  float ay = aflow[(((size_t)b * 2 + 1) * H_ + y1) * W_ + x1];
  int x2 = (int)(ax + 0.5f), y2 = (int)(ay + 0.5f);

  int NP = P + NN;
  for (int p0 = 0; p0 < NP; p0 += 16){
    int p = p0 + grp;
    float s = 0.0f;
    if (p < NP){
      int ox, oy;
      if (p < P){ ox = pos[p]; oy = pos[P + p]; }
      else      { ox = neg[p - P]; oy = neg[NN + p - P]; }
      int px = min(max(x2 + ox, 0), W_ - 1);
      int py = min(max(y2 + oy, 0), H_ - 1);
      if (USE_T){
        const uint4 v = *reinterpret_cast<const uint4*>(
            f2t + (((size_t)b * H_ + py) * W_ + px) * D_ + l16 * 8);
        s = a[0]*bf_lo(v.x) + a[1]*bf_hi(v.x) + a[2]*bf_lo(v.y) + a[3]*bf_hi(v.y)
          + a[4]*bf_lo(v.z) + a[5]*bf_hi(v.z) + a[6]*bf_lo(v.w) + a[7]*bf_hi(v.w);
      } else {
        size_t o = (((size_t)b * D_ + l16 * 8) * H_ + py) * W_ + px;
        #pragma unroll
        for (int j = 0; j < 8; ++j) s += a[j] * feat2[o + (size_t)j * H_ * W_];
      }
    }
    s += __shfl_xor(s, 1); s += __shfl_xor(s, 2);
    s += __shfl_xor(s, 4); s += __shfl_xor(s, 8);
    if (p < NP && l16 == 0){
      size_t idx = (size_t)n * NCOL + p;
      out[idx] = s;
      out[GTOFF + idx] = (p < P) ? 1.0f : 0.0f;   // gt zeroed by gtzero_k before
    }
  }
}

// ---- dscores GEMM: barrier-free wave-flow, WIDE nt drain ----
// Each wave: 16 rows x one 256-col span. Mask applied at STAGE time; staging
// is shifted per-row by h so the drain body is a guaranteed-16B-aligned f32x4
// nt store: ONE ~1KB instruction per row (the gtzero/fill pattern), head/tail
// are parallel predicated single stores. No barriers anywhere.
__global__ __launch_bounds__(256) void gemm_k(
    const __hip_bfloat16* __restrict__ f1o, const __hip_bfloat16* __restrict__ d3o,
    const float2* __restrict__ qxy, const float2* __restrict__ dxy,
    float* __restrict__ out, int NCOL, int CB)
{
  __shared__ float sT[4][16][264];
  int m0 = blockIdx.x * 16;
  int tid = threadIdx.x;
  int lane = tid & 63, wid = tid >> 6;
  int r16 = lane & 15, kg = lane >> 4;

  int span = blockIdx.y * 4 + wid;          // 0..31; 29..31 idle
  if (span >= 29) return;                   // safe: no barriers in kernel
  int c0 = span * 256;
  int ncols = NQ_ - c0; if (ncols > 256) ncols = 256;   // 256, or 32 (span 28)
  int nj = (ncols + 15) >> 4;               // 16 or 2

  // A fragments: 16 rows x K=128 in registers
  short8 af[4];
  #pragma unroll
  for (int ks = 0; ks < 4; ++ks)
    af[ks] = *reinterpret_cast<const short8*>(
        f1o + (size_t)(m0 + r16) * D_ + ks * 32 + kg * 8);

  // my staged row's alignment shift
  size_t Sr = (size_t)(m0 + r16) * NCOL + CB + c0;
  int hme = (int)((4 - (Sr & 3)) & 3);
  float2 q = qxy[m0 + r16];

  #pragma unroll
  for (int j = 0; j < 16; ++j){
    if (j < nj){
      int nn = c0 + j * 16 + r16;           // B-row for MFMA
      f32x4 acc = {0.f, 0.f, 0.f, 0.f};
      #pragma unroll
      for (int ks = 0; ks < 4; ++ks){
        short8 br = *reinterpret_cast<const short8*>(
            d3o + (size_t)nn * D_ + ks * 32 + kg * 8);
        acc = __builtin_amdgcn_mfma_f32_16x16x32_bf16(br, af[ks], acc, 0, 0, 0);
      }
      // lane holds scores[m0+r16][c0 + j*16 + kg*4 + t]; mask now, stage shifted
      int nb0 = c0 + j * 16 + kg * 4;
      f32x4 d01 = *reinterpret_cast<const f32x4*>(dxy + nb0);      // cols nb0, nb0+1
      f32x4 d23 = *reinterpret_cast<const f32x4*>(dxy + nb0 + 2);  // cols nb0+2, nb0+3
      float ddx0 = q.x - d01[0], ddy0 = q.y - d01[1];
      float ddx1 = q.x - d01[2], ddy1 = q.y - d01[3];
      float ddx2 = q.x - d23[0], ddy2 = q.y - d23[1];
      float ddx3 = q.x - d23[2], ddy3 = q.y - d23[3];
      if (ddx0 * ddx0 + ddy0 * ddy0 < 16.0f) acc[0] = 0.0f;
      if (ddx1 * ddx1 + ddy1 * ddy1 < 16.0f) acc[1] = 0.0f;
      if (ddx2 * ddx2 + ddy2 * ddy2 < 16.0f) acc[2] = 0.0f;
      if (ddx3 * ddx3 + ddy3 * ddy3 < 16.0f) acc[3] = 0.0f;
      int base = 4 + j * 16 + kg * 4 - hme;
      sT[wid][r16][base + 0] = acc[0];
      sT[wid][r16][base + 1] = acc[1];
      sT[wid][r16][base + 2] = acc[2];
      sT[wid][r16][base + 3] = acc[3];
    }
  }
  // wave-private LDS, in-order within wave: no barrier needed before drain

  // drain: per row ONE aligned full-wave nt f32x4 store + predicated head/tail
  #pragma unroll 1
  for (int r = 0; r < 16; ++r){
    size_t S = (size_t)(m0 + r) * NCOL + CB + c0;
    int h = (int)((4 - (S & 3)) & 3);
    int nb = (ncols - h) >> 2;
    const float* row = &sT[wid][r][0];
    if (lane < nb){
      f32x4 v = *reinterpret_cast<const f32x4*>(row + 4 + 4 * lane);  // 16B aligned
      __builtin_nontemporal_store(v, reinterpret_cast<f32x4*>(out + S + h + 4 * lane));
    }
    if (lane < h)
      __builtin_nontemporal_store(row[4 + lane - h], out + S + lane);
    int t0 = h + nb * 4;
    if (lane < ncols - t0)
      __builtin_nontemporal_store(row[4 + t0 + lane - h], out + S + t0 + lane);
  }
}

extern "C" void kernel_launch(void* const* d_in, const int* in_sizes, int n_in,
                              void* d_out, int out_size, void* d_ws, size_t ws_size,
                              hipStream_t stream)
{
  const float* feat1 = (const float*)d_in[0];
  const float* feat2 = (const float*)d_in[1];
  const float* conf1 = (const float*)d_in[2];
  const float* aflow = (const float*)d_in[4];
  const int* pos = (const int*)d_in[5];
  const int* neg = (const int*)d_in[6];
  int P = in_sizes[5] / 2, NN = in_sizes[6] / 2;
  int NCOL = P + NN + NQ_;
  size_t GTOFF = (size_t)NQ_ * (size_t)NCOL;
  float* out = (float*)d_out;

  char* ws = (char*)d_ws;
  __hip_bfloat16* f1o = (__hip_bfloat16*)ws;                     // 1,843,200 B
  __hip_bfloat16* d3o = (__hip_bfloat16*)(ws + 1843200);         // 1,843,200 B
  float2* qxy = (float2*)(ws + 3686400);                         // 57,600 B
  float2* dxy = (float2*)(ws + 3744000);                         // 57,600 B
  __hip_bfloat16* f2t = (__hip_bfloat16*)(ws + 3801600);         // 134,217,728 B
  size_t needT = 3801600ull + (size_t)B_ * H_ * W_ * D_ * 2;
  bool useT = ws_size >= needT;

  float* omask  = out + 2 * GTOFF;
  float* oqconf = omask + NQ_;

  // zero the full gt region (posneg then writes cols 0..P+NN-1)
  gtzero_k<<<2048, 256, 0, stream>>>((f32x4*)(out + GTOFF), GTOFF / 4);

  if (useT){
    transpose_k<<<dim3(W_ / 64, H_, B_), 256, 0, stream>>>(feat2, f2t);
    prep_k<true><<<NQ_, 128, 0, stream>>>(feat1, feat2, f2t, conf1, aflow,
                                          f1o, d3o, qxy, dxy, omask, oqconf);
    gemm_k<<<dim3(NQ_ / 16, 8), 256, 0, stream>>>(f1o, d3o, qxy, dxy,
                                                  out, NCOL, P + NN);
    posneg_k<true><<<NQ_, 256, 0, stream>>>(f1o, f2t, feat2, aflow, pos, neg,
                                            P, NN, out, NCOL, GTOFF);
  } else {
    prep_k<false><<<NQ_, 128, 0, stream>>>(feat1, feat2, f2t, conf1, aflow,
                                           f1o, d3o, qxy, dxy, omask, oqconf);
    gemm_k<<<dim3(NQ_ / 16, 8), 256, 0, stream>>>(f1o, d3o, qxy, dxy,
                                                  out, NCOL, P + NN);
    posneg_k<false><<<NQ_, 256, 0, stream>>>(f1o, f2t, feat2, aflow, pos, neg,
                                             P, NN, out, NCOL, GTOFF);
  }
}

// Round 20
// 289.225 us; speedup vs baseline: 1.0734x; 1.0734x over previous
//
#include <hip/hip_runtime.h>
#include <hip/hip_bf16.h>
#include <stdint.h>

#define B_ 2
#define D_ 128
#define H_ 512
#define W_ 512
#define G_ 60
#define NQ_ 7200
#define BORDER_ 16
#define STEP_ 8

typedef __attribute__((ext_vector_type(8))) short short8;
typedef __attribute__((ext_vector_type(4))) float f32x4;
typedef __attribute__((ext_vector_type(4))) uint32_t u32x4;

__device__ __forceinline__ float bf_lo(uint32_t u){ return __builtin_bit_cast(float, u << 16); }
__device__ __forceinline__ float bf_hi(uint32_t u){ return __builtin_bit_cast(float, u & 0xffff0000u); }

__device__ __forceinline__ uint32_t pack2bf(float lo, float hi){
  uint16_t l = __builtin_bit_cast(uint16_t, __float2bfloat16(lo));
  uint16_t h = __builtin_bit_cast(uint16_t, __float2bfloat16(hi));
  return (uint32_t)l | ((uint32_t)h << 16);
}

// ---------------- gt region zero-fill (aligned full-line nt float4 stream) ----------------
__global__ __launch_bounds__(256) void gtzero_k(f32x4* __restrict__ gt, size_t n4){
  size_t i = (size_t)blockIdx.x * 256 + threadIdx.x;
  size_t stride = (size_t)gridDim.x * 256;
  f32x4 z = {0.f, 0.f, 0.f, 0.f};
  for (; i < n4; i += stride)
    __builtin_nontemporal_store(z, gt + i);
}

// ---------------- feat2 (B,D,H,W) f32 -> (B,H,W,D) bf16 ----------------
__global__ __launch_bounds__(256) void transpose_k(const float* __restrict__ src,
                                                   __hip_bfloat16* __restrict__ dst){
  __shared__ uint32_t lds2[64][65];
  int b = blockIdx.z, y = blockIdx.y, x0 = blockIdx.x * 64;
  int tid = threadIdx.x;
  size_t plane = (size_t)H_ * W_;

  int xq = tid & 15;        // x-quad (4 floats)
  int eg = tid >> 4;        // 0..15
  size_t base_in = (((size_t)b * D_) * H_ + y) * W_ + x0 + 4 * xq;
  #pragma unroll
  for (int it = 0; it < 4; ++it){
    int e = eg + 16 * it;   // d-pair 0..63
    f32x4 lo = __builtin_nontemporal_load(
        reinterpret_cast<const f32x4*>(src + base_in + (size_t)(2 * e) * plane));
    f32x4 hi = __builtin_nontemporal_load(
        reinterpret_cast<const f32x4*>(src + base_in + (size_t)(2 * e + 1) * plane));
    lds2[e][4 * xq + 0] = pack2bf(lo[0], hi[0]);
    lds2[e][4 * xq + 1] = pack2bf(lo[1], hi[1]);
    lds2[e][4 * xq + 2] = pack2bf(lo[2], hi[2]);
    lds2[e][4 * xq + 3] = pack2bf(lo[3], hi[3]);
  }
  __syncthreads();

  int eq = tid & 15;        // u32-quad within a pixel's 64-u32 row
  int xb = tid >> 4;        // 0..15
  size_t pixbase = (((size_t)b * H_ + y) * W_ + x0);
  #pragma unroll
  for (int it = 0; it < 4; ++it){
    int x = xb + 16 * it;
    u32x4 v;
    v[0] = lds2[4 * eq + 0][x];
    v[1] = lds2[4 * eq + 1][x];
    v[2] = lds2[4 * eq + 2][x];
    v[3] = lds2[4 * eq + 3][x];
    *reinterpret_cast<u32x4*>(dst + (pixbase + x) * D_ + 8 * eq) = v;
  }
}

// ---------------- per-query prep: f1, d3, xy tables, mask, qconf ----------------
template<bool USE_T>
__global__ __launch_bounds__(128) void prep_k(
    const float* __restrict__ feat1, const float* __restrict__ feat2,
    const __hip_bfloat16* __restrict__ f2t,
    const float* __restrict__ conf1, const float* __restrict__ aflow,
    __hip_bfloat16* __restrict__ f1o, __hip_bfloat16* __restrict__ d3o,
    float2* __restrict__ qxy, float2* __restrict__ dxy,
    float* __restrict__ omask, float* __restrict__ oqconf)
{
  int n = blockIdx.x;
  int b = n / (G_ * G_); int r = n % (G_ * G_);
  int iy = r / G_, ix = r % G_;
  int y1 = BORDER_ + iy * STEP_, x1 = BORDER_ + ix * STEP_;
  int tid = threadIdx.x;
  size_t pix = ((size_t)b * H_ + y1) * W_ + x1;
  if (tid < 64){
    int d = tid * 2;
    size_t o = (((size_t)b * D_ + d) * H_ + y1) * W_ + x1;
    float lo = feat1[o];
    float hi = feat1[o + (size_t)H_ * W_];
    *reinterpret_cast<uint32_t*>(f1o + (size_t)n * D_ + d) = pack2bf(lo, hi);
    if (tid == 0){
      float ax = aflow[(((size_t)b * 2 + 0) * H_ + y1) * W_ + x1];
      float ay = aflow[(((size_t)b * 2 + 1) * H_ + y1) * W_ + x1];
      int x2 = (int)(ax + 0.5f);   // trunc toward zero == astype(int32)
      int y2 = (int)(ay + 0.5f);
      omask[n] = (x2 >= 0 && y2 >= 0 && x2 < W_ && y2 < H_) ? 1.0f : 0.0f;
      oqconf[n] = conf1[pix];
      float bs = 512.0f * (float)b;
      qxy[n] = make_float2((float)x2 + bs, (float)y2 + bs);
      dxy[n] = make_float2((float)x1 + bs, (float)y1 + bs);
    }
  } else {
    int d = (tid - 64) * 2;
    uint32_t u;
    if (USE_T){
      u = *reinterpret_cast<const uint32_t*>(f2t + pix * D_ + d);
    } else {
      size_t o = (((size_t)b * D_ + d) * H_ + y1) * W_ + x1;
      u = pack2bf(feat2[o], feat2[o + (size_t)H_ * W_]);
    }
    *reinterpret_cast<uint32_t*>(d3o + (size_t)n * D_ + d) = u;
  }
}

// ---------------- pos/neg neighbor scores + gt cols 0..P+NN-1 ----------------
template<bool USE_T>
__global__ __launch_bounds__(256) void posneg_k(
    const __hip_bfloat16* __restrict__ f1o,
    const __hip_bfloat16* __restrict__ f2t,
    const float* __restrict__ feat2,
    const float* __restrict__ aflow,
    const int* __restrict__ pos, const int* __restrict__ neg,
    int P, int NN, float* __restrict__ out, int NCOL, size_t GTOFF)
{
  int n = blockIdx.x;
  int b = n / (G_ * G_); int r = n % (G_ * G_);
  int iy = r / G_, ix = r % G_;
  int y1 = BORDER_ + iy * STEP_, x1 = BORDER_ + ix * STEP_;
  int tid = threadIdx.x;
  int l16 = tid & 15, grp = tid >> 4;

  const uint4 av = *reinterpret_cast<const uint4*>(f1o + (size_t)n * D_ + l16 * 8);
  float a[8];
  a[0] = bf_lo(av.x); a[1] = bf_hi(av.x); a[2] = bf_lo(av.y); a[3] = bf_hi(av.y);
  a[4] = bf_lo(av.z); a[5] = bf_hi(av.z); a[6] = bf_lo(av.w); a[7] = bf_hi(av.w);

  float ax = aflow[(((size_t)b * 2 + 0) * H_ + y1) * W_ + x1];
  float ay = aflow[(((size_t)b * 2 + 1) * H_ + y1) * W_ + x1];
  int x2 = (int)(ax + 0.5f), y2 = (int)(ay + 0.5f);

  int NP = P + NN;
  for (int p0 = 0; p0 < NP; p0 += 16){
    int p = p0 + grp;
    float s = 0.0f;
    if (p < NP){
      int ox, oy;
      if (p < P){ ox = pos[p]; oy = pos[P + p]; }
      else      { ox = neg[p - P]; oy = neg[NN + p - P]; }
      int px = min(max(x2 + ox, 0), W_ - 1);
      int py = min(max(y2 + oy, 0), H_ - 1);
      if (USE_T){
        const uint4 v = *reinterpret_cast<const uint4*>(
            f2t + (((size_t)b * H_ + py) * W_ + px) * D_ + l16 * 8);
        s = a[0]*bf_lo(v.x) + a[1]*bf_hi(v.x) + a[2]*bf_lo(v.y) + a[3]*bf_hi(v.y)
          + a[4]*bf_lo(v.z) + a[5]*bf_hi(v.z) + a[6]*bf_lo(v.w) + a[7]*bf_hi(v.w);
      } else {
        size_t o = (((size_t)b * D_ + l16 * 8) * H_ + py) * W_ + px;
        #pragma unroll
        for (int j = 0; j < 8; ++j) s += a[j] * feat2[o + (size_t)j * H_ * W_];
      }
    }
    s += __shfl_xor(s, 1); s += __shfl_xor(s, 2);
    s += __shfl_xor(s, 4); s += __shfl_xor(s, 8);
    if (p < NP && l16 == 0){
      size_t idx = (size_t)n * NCOL + p;
      out[idx] = s;
      out[GTOFF + idx] = (p < P) ? 1.0f : 0.0f;   // gt zeroed by gtzero_k before
    }
  }
}

// ---- dscores GEMM: wave-flow + B-operand register double-buffer ----
// Key idea (R17/R18 diagnosis): vmcnt is a shared in-order FIFO for loads AND
// stores. If next-chunk loads are issued BEFORE this chunk's stores, the next
// MFMA's s_waitcnt is satisfied as soon as the (older) loads retire, leaving
// the nt stores to drain UNDER the compute. Strict A/B alternation keeps
// buffer lifetimes disjoint (register-friendly, all indices static).
__global__ __launch_bounds__(256) void gemm_k(
    const __hip_bfloat16* __restrict__ f1o, const __hip_bfloat16* __restrict__ d3o,
    const float2* __restrict__ qxy, const float2* __restrict__ dxy,
    float* __restrict__ out, int NCOL, int CB)
{
  __shared__ float sT[4][16][100];
  int m0 = blockIdx.x * 16;
  int tid = threadIdx.x;
  int lane = tid & 63, wid = tid >> 6;
  int r16 = lane & 15, kg = lane >> 4;
  int cbase = blockIdx.y * 16 + wid * 4;   // 4 consecutive chunks per wave

  // A fragments: 16 rows x K=128 in registers
  short8 af[4];
  #pragma unroll
  for (int ks = 0; ks < 4; ++ks)
    af[ks] = *reinterpret_cast<const short8*>(
        f1o + (size_t)(m0 + r16) * D_ + ks * 32 + kg * 8);

  short8 bufA[6][4], bufB[6][4];

  auto load_chunk = [&](short8 (&bn)[6][4], int c){
    int cn0 = c * 64;
    int nj = (c == 111) ? 6 : 4;           // tail chunk has 96 cols
    #pragma unroll
    for (int j = 0; j < 6; ++j)
      if (j < nj){
        int nn = cn0 + j * 16 + r16;
        #pragma unroll
        for (int ks = 0; ks < 4; ++ks)
          bn[j][ks] = *reinterpret_cast<const short8*>(
              d3o + (size_t)nn * D_ + ks * 32 + kg * 8);
      }
  };

  auto compute_stage = [&](short8 (&bn)[6][4], int c){
    int nj = (c == 111) ? 6 : 4;
    #pragma unroll
    for (int j = 0; j < 6; ++j)
      if (j < nj){
        f32x4 acc = {0.f, 0.f, 0.f, 0.f};
        #pragma unroll
        for (int ks = 0; ks < 4; ++ks)
          acc = __builtin_amdgcn_mfma_f32_16x16x32_bf16(bn[j][ks], af[ks], acc, 0, 0, 0);
        *reinterpret_cast<f32x4*>(&sT[wid][r16][j * 16 + kg * 4]) = acc;
      }
  };

  auto drain = [&](int c){
    int cn0 = c * 64;
    int nc = (c == 111) ? 96 : 64;
    float2 dcA = dxy[cn0 + lane];
    float2 dcB = dxy[cn0 + ((nc > 64) ? 64 + (lane & 31) : lane)];
    size_t S = (size_t)m0 * NCOL + CB + cn0;
    #pragma unroll
    for (int r = 0; r < 16; ++r, S += NCOL){
      float2 q = qxy[m0 + r];
      float v = sT[wid][r][lane];
      float ddx = q.x - dcA.x, ddy = q.y - dcA.y;
      float val = (ddx * ddx + ddy * ddy < 16.0f) ? 0.0f : v;
      __builtin_nontemporal_store(val, out + S + lane);
      if (nc > 64 && lane < 32){
        float v2 = sT[wid][r][64 + lane];
        float ddx2 = q.x - dcB.x, ddy2 = q.y - dcB.y;
        float val2 = (ddx2 * ddx2 + ddy2 * ddy2 < 16.0f) ? 0.0f : v2;
        __builtin_nontemporal_store(val2, out + S + 64 + lane);
      }
    }
  };

  // software pipeline: loads of chunk k+1 issued BEFORE stores of chunk k
  load_chunk(bufA, cbase + 0);
  compute_stage(bufA, cbase + 0);      // bufA dead
  load_chunk(bufB, cbase + 1);         // loads enter vmcnt FIFO first...
  drain(cbase + 0);                    // ...then stores: compute(k+1) won't wait on them
  compute_stage(bufB, cbase + 1);      // bufB dead
  load_chunk(bufA, cbase + 2);
  drain(cbase + 1);
  compute_stage(bufA, cbase + 2);
  load_chunk(bufB, cbase + 3);
  drain(cbase + 2);
  compute_stage(bufB, cbase + 3);
  drain(cbase + 3);
}

extern "C" void kernel_launch(void* const* d_in, const int* in_sizes, int n_in,
                              void* d_out, int out_size, void* d_ws, size_t ws_size,
                              hipStream_t stream)
{
  const float* feat1 = (const float*)d_in[0];
  const float* feat2 = (const float*)d_in[1];
  const float* conf1 = (const float*)d_in[2];
  const float* aflow = (const float*)d_in[4];
  const int* pos = (const int*)d_in[5];
  const int* neg = (const int*)d_in[6];
  int P = in_sizes[5] / 2, NN = in_sizes[6] / 2;
  int NCOL = P + NN + NQ_;
  size_t GTOFF = (size_t)NQ_ * (size_t)NCOL;
  float* out = (float*)d_out;

  char* ws = (char*)d_ws;
  __hip_bfloat16* f1o = (__hip_bfloat16*)ws;                     // 1,843,200 B
  __hip_bfloat16* d3o = (__hip_bfloat16*)(ws + 1843200);         // 1,843,200 B
  float2* qxy = (float2*)(ws + 3686400);                         // 57,600 B
  float2* dxy = (float2*)(ws + 3744000);                         // 57,600 B
  __hip_bfloat16* f2t = (__hip_bfloat16*)(ws + 3801600);         // 134,217,728 B
  size_t needT = 3801600ull + (size_t)B_ * H_ * W_ * D_ * 2;
  bool useT = ws_size >= needT;

  float* omask  = out + 2 * GTOFF;
  float* oqconf = omask + NQ_;

  // zero the full gt region (posneg then writes cols 0..P+NN-1)
  gtzero_k<<<2048, 256, 0, stream>>>((f32x4*)(out + GTOFF), GTOFF / 4);

  if (useT){
    transpose_k<<<dim3(W_ / 64, H_, B_), 256, 0, stream>>>(feat2, f2t);
    prep_k<true><<<NQ_, 128, 0, stream>>>(feat1, feat2, f2t, conf1, aflow,
                                          f1o, d3o, qxy, dxy, omask, oqconf);
    gemm_k<<<dim3(NQ_ / 16, 7), 256, 0, stream>>>(f1o, d3o, qxy, dxy,
                                                  out, NCOL, P + NN);
    posneg_k<true><<<NQ_, 256, 0, stream>>>(f1o, f2t, feat2, aflow, pos, neg,
                                            P, NN, out, NCOL, GTOFF);
  } else {
    prep_k<false><<<NQ_, 128, 0, stream>>>(feat1, feat2, f2t, conf1, aflow,
                                           f1o, d3o, qxy, dxy, omask, oqconf);
    gemm_k<<<dim3(NQ_ / 16, 7), 256, 0, stream>>>(f1o, d3o, qxy, dxy,
                                                  out, NCOL, P + NN);
    posneg_k<false><<<NQ_, 256, 0, stream>>>(f1o, f2t, feat2, aflow, pos, neg,
                                             P, NN, out, NCOL, GTOFF);
  }
}